// Round 1
// baseline (107.999 us; speedup 1.0000x reference)
//
#include <hip/hip_runtime.h>

#define WID 256          // W
#define HTOT 1280        // num_img * H = 5 * 256
#define RPB 64           // rows per block (stripe height)
#define BPB (HTOT / RPB) // 20 blocks per batch
#define BS 64            // batch size
#define NEG_FILL -1e9f

struct Cand { float v; int i; };

__device__ __forceinline__ bool better(float av, int ai, float bv, int bi) {
    // strict total order: larger value wins; tie -> smaller flat index (XLA top_k tie-break)
    return (av > bv) || (av == bv && ai < bi);
}

__device__ __forceinline__ void insert3(float cv, int ci,
                                        float& v0, int& i0,
                                        float& v1, int& i1,
                                        float& v2, int& i2) {
    if (better(cv, ci, v2, i2)) {
        if (better(cv, ci, v1, i1)) {
            if (better(cv, ci, v0, i0)) {
                v2 = v1; i2 = i1; v1 = v0; i1 = i0; v0 = cv; i0 = ci;
            } else {
                v2 = v1; i2 = i1; v1 = cv; i1 = ci;
            }
        } else {
            v2 = cv; i2 = ci;
        }
    }
}

__global__ __launch_bounds__(256) void peaks_phase1(const float* __restrict__ hm,
                                                    Cand* __restrict__ ws) {
    const int c  = threadIdx.x;      // column 0..255
    const int b  = blockIdx.y;       // batch
    const int r0 = blockIdx.x * RPB; // first output row of this stripe
    const float NINF = -__builtin_inff();

    __shared__ float buf[2][WID + 4];   // horizontal line buffer, 2-col halo each side
    if (c < 2) {
        buf[0][c] = NINF; buf[1][c] = NINF;
        buf[0][WID + 2 + c] = NINF; buf[1][WID + 2 + c] = NINF;
    }

    const float* base = hm + (size_t)b * (size_t)(HTOT * WID);

    // vertical shift chains (static indexing -> stays in VGPRs)
    float h0 = NINF, h1 = NINF, h2 = NINF, h3 = NINF, h4 = NINF; // horiz max of rows rr-4..rr
    float raw0 = NINF, raw1 = NINF, raw2 = NINF;                 // raw values rows rr-2..rr

    float v0 = NINF, v1 = NINF, v2 = NINF;
    int   i0 = 0,    i1 = 0,    i2 = 0;

    int p = 0;
    for (int rr = r0 - 2; rr <= r0 + RPB + 1; ++rr) {
        float val = NINF;
        if (rr >= 0 && rr < HTOT) val = base[(size_t)rr * WID + c];
        buf[p][2 + c] = val;
        __syncthreads();
        float m = fmaxf(fmaxf(buf[p][c], buf[p][c + 1]), buf[p][c + 2]);
        m = fmaxf(m, fmaxf(buf[p][c + 3], buf[p][c + 4]));
        // shift chains
        h0 = h1; h1 = h2; h2 = h3; h3 = h4; h4 = m;
        raw0 = raw1; raw1 = raw2; raw2 = val;   // raw0 = raw[rr-2]
        const int rout = rr - 2;
        if (rout >= r0 && rout < r0 + RPB) {
            float wmax = fmaxf(fmaxf(fmaxf(h0, h1), fmaxf(h2, h3)), h4);
            float cand = (raw0 == wmax) ? raw0 : NEG_FILL;
            insert3(cand, rout * WID + c, v0, i0, v1, i1, v2, i2);
        }
        p ^= 1;
    }

    // block tree-reduction of per-thread top-3
    __shared__ float rv[256][3];
    __shared__ int   ri[256][3];
    rv[c][0] = v0; rv[c][1] = v1; rv[c][2] = v2;
    ri[c][0] = i0; ri[c][1] = i1; ri[c][2] = i2;
    __syncthreads();
    for (int s = 128; s > 0; s >>= 1) {
        if (c < s) {
            insert3(rv[c + s][0], ri[c + s][0], v0, i0, v1, i1, v2, i2);
            insert3(rv[c + s][1], ri[c + s][1], v0, i0, v1, i1, v2, i2);
            insert3(rv[c + s][2], ri[c + s][2], v0, i0, v1, i1, v2, i2);
            rv[c][0] = v0; rv[c][1] = v1; rv[c][2] = v2;
            ri[c][0] = i0; ri[c][1] = i1; ri[c][2] = i2;
        }
        __syncthreads();
    }
    if (c == 0) {
        Cand* o = ws + ((size_t)b * BPB + blockIdx.x) * 3;
        o[0].v = v0; o[0].i = i0;
        o[1].v = v1; o[1].i = i1;
        o[2].v = v2; o[2].i = i2;
    }
}

__global__ __launch_bounds__(64) void peaks_phase2(const Cand* __restrict__ ws,
                                                   float* __restrict__ out) {
    const int b = blockIdx.x;
    const int t = threadIdx.x;
    const int NC = BPB * 3; // 60 candidates per batch
    const float NINF = -__builtin_inff();

    float v0 = NINF, v1 = NINF, v2 = NINF;
    int   i0 = 0,    i1 = 0,    i2 = 0;
    if (t < NC) {
        Cand e = ws[(size_t)b * NC + t];
        v0 = e.v; i0 = e.i;
    }

    __shared__ float rv[64][3];
    __shared__ int   ri[64][3];
    rv[t][0] = v0; rv[t][1] = v1; rv[t][2] = v2;
    ri[t][0] = i0; ri[t][1] = i1; ri[t][2] = i2;
    __syncthreads();
    for (int s = 32; s > 0; s >>= 1) {
        if (t < s) {
            insert3(rv[t + s][0], ri[t + s][0], v0, i0, v1, i1, v2, i2);
            insert3(rv[t + s][1], ri[t + s][1], v0, i0, v1, i1, v2, i2);
            insert3(rv[t + s][2], ri[t + s][2], v0, i0, v1, i1, v2, i2);
            rv[t][0] = v0; rv[t][1] = v1; rv[t][2] = v2;
            ri[t][0] = i0; ri[t][1] = i1; ri[t][2] = i2;
        }
        __syncthreads();
    }

    if (t == 0) {
        const float vs0 = v0, vs1 = v1, vs2 = v2;
        const int   is0 = i0, is1 = i1, is2 = i2;
        // positions: [bs,3,3] at offset 0 ; scores: [bs,3] at 576 ; mask: [bs,3] at 768
        float* pos = out + (size_t)b * 9;
        float* sco = out + 576 + (size_t)b * 3;
        float* msk = out + 768 + (size_t)b * 3;

        // k = 0
        pos[0] = (float)(is0 >> 16);
        pos[1] = (float)((is0 >> 8) & 255);
        pos[2] = (float)(is0 & 255);
        sco[0] = vs0;
        msk[0] = (vs0 > -1e30f) ? 1.0f : 0.0f;
        // k = 1
        pos[3] = (float)(is1 >> 16);
        pos[4] = (float)((is1 >> 8) & 255);
        pos[5] = (float)(is1 & 255);
        sco[1] = vs1;
        msk[1] = (vs1 > -1e30f) ? 1.0f : 0.0f;
        // k = 2
        pos[6] = (float)(is2 >> 16);
        pos[7] = (float)((is2 >> 8) & 255);
        pos[8] = (float)(is2 & 255);
        sco[2] = vs2;
        msk[2] = (vs2 > -1e30f) ? 1.0f : 0.0f;
    }
}

extern "C" void kernel_launch(void* const* d_in, const int* in_sizes, int n_in,
                              void* d_out, int out_size, void* d_ws, size_t ws_size,
                              hipStream_t stream) {
    const float* hm = (const float*)d_in[0];
    float* out = (float*)d_out;
    Cand* ws = (Cand*)d_ws;  // needs 64*20*3*8 = 30720 bytes

    dim3 g1(BPB, BS);
    peaks_phase1<<<g1, 256, 0, stream>>>(hm, ws);
    peaks_phase2<<<BS, 64, 0, stream>>>(ws, out);
}